// Round 3
// baseline (502.150 us; speedup 1.0000x reference)
//
#include <hip/hip_runtime.h>

#define NR 4096
#define BN_EPS 1e-5f

// ---- d_out offsets (floats), concatenated in reference return order ----
#define OFF_LATENT 0
#define OFF_D1     131072
#define OFF_D2     172032
#define OFF_Q      212992
#define OFF_P      16990208
#define OFF_NUM    33767424
#define OFF_NORM   50544640

// ---- workspace offsets (floats) — small accumulators only (~85 KB) ----
#define WS_SUM0   0
#define WS_SQ0    256
#define WS_SUM1   512
#define WS_SQ1    576
#define WS_ROWSUM 640
#define WS_ZERO_F 4736          // floats to zero (atomic accumulators)
#define WS_DIAG   4736
#define WS_SUMY   8832
// H0 [4096x256] and H1 [4096x64] live in d_out's latent_q region (written last)

// ============ zero the atomic accumulators (graph-capture-safe) ============
__global__ void zero_ws(float* __restrict__ ws) {
    int i = blockIdx.x * blockDim.x + threadIdx.x;
    if (i < WS_ZERO_F) ws[i] = 0.0f;
}

// ============ init H0 with bias (split-K GEMM accumulates on top) ============
__global__ void h0_init(float* __restrict__ H0, const float* __restrict__ b0) {
    int i4 = blockIdx.x * blockDim.x + threadIdx.x;     // over 262144 float4
    ((float4*)H0)[i4] = ((const float4*)b0)[i4 & 63];   // 256 cols = 64 float4
}

// ============ GEMM0: C += A[M,K] @ B[N,K]^T, split-K, atomic ============
// 128x64 tile, 8x4 micro-tile, BK=16, 256 threads
__global__ __launch_bounds__(256) void gemm_splitk_128x64(
    const float* __restrict__ A, const float* __restrict__ B,
    float* __restrict__ C, int lda, int ldb, int ldc, int kc)
{
    __shared__ float As[16][128];   // transposed: As[k][row]
    __shared__ float Bs[16][64];
    const int t  = threadIdx.x;
    const int tx = t & 15;          // col group (4 cols)
    const int ty = t >> 4;          // row group (8 rows)
    const int i0 = blockIdx.x * 128;
    const int n0 = blockIdx.y * 64;
    const int kb = blockIdx.z * kc;

    const int ra  = t >> 1;         // 0..127 (A row)
    const int ka  = (t & 1) * 8;    // 0 or 8
    const int rb  = t >> 2;         // 0..63  (B row)
    const int kbq = (t & 3) * 4;    // 0,4,8,12

    float acc[8][4] = {};

    for (int kt = 0; kt < kc; kt += 16) {
        float4 a0 = *(const float4*)&A[(size_t)(i0 + ra) * lda + kb + kt + ka];
        float4 a1 = *(const float4*)&A[(size_t)(i0 + ra) * lda + kb + kt + ka + 4];
        float4 b0 = *(const float4*)&B[(size_t)(n0 + rb) * ldb + kb + kt + kbq];
        __syncthreads();
        As[ka+0][ra] = a0.x; As[ka+1][ra] = a0.y; As[ka+2][ra] = a0.z; As[ka+3][ra] = a0.w;
        As[ka+4][ra] = a1.x; As[ka+5][ra] = a1.y; As[ka+6][ra] = a1.z; As[ka+7][ra] = a1.w;
        Bs[kbq+0][rb] = b0.x; Bs[kbq+1][rb] = b0.y; Bs[kbq+2][rb] = b0.z; Bs[kbq+3][rb] = b0.w;
        __syncthreads();
        #pragma unroll
        for (int k = 0; k < 16; ++k) {
            float4 av0 = *(const float4*)&As[k][ty*8];
            float4 av1 = *(const float4*)&As[k][ty*8+4];
            float4 bv  = *(const float4*)&Bs[k][tx*4];
            float am[8] = {av0.x,av0.y,av0.z,av0.w,av1.x,av1.y,av1.z,av1.w};
            float bb[4] = {bv.x,bv.y,bv.z,bv.w};
            #pragma unroll
            for (int m = 0; m < 8; ++m)
                #pragma unroll
                for (int n = 0; n < 4; ++n)
                    acc[m][n] = fmaf(am[m], bb[n], acc[m][n]);
        }
    }
    #pragma unroll
    for (int m = 0; m < 8; ++m)
        #pragma unroll
        for (int n = 0; n < 4; ++n)
            atomicAdd(&C[(size_t)(i0 + ty*8 + m) * ldc + n0 + tx*4 + n], acc[m][n]);
}

// ============ GEMM (small): C = A @ B^T + bias, 64x64 tile, 4x4 micro ============
__global__ __launch_bounds__(256) void gemm_bias_64x64(
    const float* __restrict__ A, const float* __restrict__ B,
    const float* __restrict__ bias, float* __restrict__ C,
    int lda, int ldb, int ldc, int K)
{
    __shared__ float As[16][64];
    __shared__ float Bs[16][64];
    const int t  = threadIdx.x;
    const int tx = t & 15, ty = t >> 4;
    const int i0 = blockIdx.x * 64;
    const int n0 = blockIdx.y * 64;
    const int r  = t >> 2;
    const int kq = (t & 3) * 4;

    float acc[4][4] = {};

    for (int kt = 0; kt < K; kt += 16) {
        float4 a4 = *(const float4*)&A[(size_t)(i0 + r) * lda + kt + kq];
        float4 b4 = *(const float4*)&B[(size_t)(n0 + r) * ldb + kt + kq];
        __syncthreads();
        As[kq+0][r] = a4.x; As[kq+1][r] = a4.y; As[kq+2][r] = a4.z; As[kq+3][r] = a4.w;
        Bs[kq+0][r] = b4.x; Bs[kq+1][r] = b4.y; Bs[kq+2][r] = b4.z; Bs[kq+3][r] = b4.w;
        __syncthreads();
        #pragma unroll
        for (int k = 0; k < 16; ++k) {
            float4 av = *(const float4*)&As[k][ty*4];
            float4 bv = *(const float4*)&Bs[k][tx*4];
            float am[4] = {av.x,av.y,av.z,av.w};
            float bb[4] = {bv.x,bv.y,bv.z,bv.w};
            #pragma unroll
            for (int m = 0; m < 4; ++m)
                #pragma unroll
                for (int n = 0; n < 4; ++n)
                    acc[m][n] = fmaf(am[m], bb[n], acc[m][n]);
        }
    }
    float4 bz = *(const float4*)&bias[n0 + tx*4];
    #pragma unroll
    for (int m = 0; m < 4; ++m) {
        float4 o;
        o.x = acc[m][0] + bz.x; o.y = acc[m][1] + bz.y;
        o.z = acc[m][2] + bz.z; o.w = acc[m][3] + bz.w;
        *(float4*)&C[(size_t)(i0 + ty*4 + m) * ldc + n0 + tx*4] = o;
    }
}

// ============ BatchNorm column stats: sum / sumsq via atomics ============
__global__ void bn_stats(const float* __restrict__ H, float* __restrict__ sum,
                         float* __restrict__ sumsq, int cols)
{
    const int t = threadIdx.x;
    const int col = t & (cols - 1);
    const int sub = t / cols;            // 0 (cols=256) or 0..3 (cols=64)
    const int rstep = 256 / cols;
    const int rbase = blockIdx.x * 64;
    float s = 0.f, sq = 0.f;
    for (int r = sub; r < 64; r += rstep) {
        float v = H[(size_t)(rbase + r) * cols + col];
        s += v; sq += v * v;
    }
    atomicAdd(&sum[col], s);
    atomicAdd(&sumsq[col], sq);
}

// ============ BN apply + ReLU (in place, float4) ============
__global__ void bn_relu(float* __restrict__ H, const float* __restrict__ sum,
                        const float* __restrict__ sumsq, const float* __restrict__ g,
                        const float* __restrict__ beta, int cols)
{
    int i4 = blockIdx.x * blockDim.x + threadIdx.x;
    float4 v = ((const float4*)H)[i4];
    int c0 = (i4 * 4) & (cols - 1);
    float o[4] = {v.x, v.y, v.z, v.w};
    #pragma unroll
    for (int e = 0; e < 4; ++e) {
        int c = c0 + e;
        float mu  = sum[c]   * (1.0f / 4096.0f);
        float var = sumsq[c] * (1.0f / 4096.0f) - mu * mu;
        float xn = (o[e] - mu) / sqrtf(var + BN_EPS);
        o[e] = fmaxf(g[c] * xn + beta[c], 0.0f);
    }
    ((float4*)H)[i4] = make_float4(o[0], o[1], o[2], o[3]);
}

// ============ latent = H1 @ W2^T + b2, fused normalize + cluster dists ============
__global__ __launch_bounds__(256) void latent_kernel(
    const float* __restrict__ H1, const float* __restrict__ W2,
    const float* __restrict__ b2, const float* __restrict__ centers,
    float* __restrict__ out_latent, float* __restrict__ out_norm,
    float* __restrict__ out_d1, float* __restrict__ out_d2,
    float* __restrict__ sumy)
{
    __shared__ float W2T[64][32];
    __shared__ float cent[320];
    __shared__ float b2s[32];
    __shared__ float Hs[8][64];
    const int t = threadIdx.x;
    {   // stage W2 transposed: W2 is [32][64] row-major
        int c = t >> 3, dd = (t & 7) * 8;
        #pragma unroll
        for (int q = 0; q < 8; ++q) W2T[dd + q][c] = W2[c * 64 + dd + q];
    }
    for (int c = t; c < 320; c += 256) cent[c] = centers[c];
    if (t < 32) b2s[t] = b2[t];
    const int base = blockIdx.x * 8;
    if (t < 128) {
        int rr = t >> 4, off = (t & 15) * 4;
        *(float4*)&Hs[rr][off] = *(const float4*)&H1[(size_t)(base + rr) * 64 + off];
    }
    __syncthreads();

    const int g = t >> 5, lane = t & 31;
    const int row = base + g;
    float acc = b2s[lane];
    #pragma unroll
    for (int d = 0; d < 64; ++d) acc = fmaf(Hs[g][d], W2T[d][lane], acc);
    out_latent[(size_t)row * 32 + lane] = acc;

    float ss = acc * acc;
    #pragma unroll
    for (int off = 16; off; off >>= 1) ss += __shfl_xor(ss, off);
    float denom = fmaxf(sqrtf(ss), 1e-12f);
    out_norm[(size_t)row * 32 + lane] = acc / denom;
    if (lane == 0) sumy[row] = ss;

    float qsum = 0.f, myx1 = 0.f, myqc = 0.f;
    #pragma unroll
    for (int k = 0; k < 10; ++k) {
        float dv = acc - cent[k * 32 + lane];
        float sq = dv * dv;
        #pragma unroll
        for (int off = 16; off; off >>= 1) sq += __shfl_xor(sq, off);
        float x1 = 1.0f + sq;
        float qc = 1.0f / x1;
        qsum += qc;
        if (lane == k) { myx1 = x1; myqc = qc; }
    }
    if (lane < 10) {
        out_d2[row * 10 + lane] = myx1;
        out_d1[row * 10 + lane] = myqc / qsum;
    }
}

// ============ num kernel: 128x128 tile of the NxN Student-t affinity ============
__global__ __launch_bounds__(256) void num_kernel(
    const float* __restrict__ latent, const float* __restrict__ sumy,
    float* __restrict__ num_out, float* __restrict__ rowsum, float* __restrict__ diagv)
{
    __shared__ float Li[128][36];   // pad 36: 144B rows, banks rotate by 4
    __shared__ float Lj[128][36];
    __shared__ float scr[128];
    const int t  = threadIdx.x;
    const int i0 = blockIdx.x * 128;
    const int j0 = blockIdx.y * 128;
    {   // stage: threads <128 -> Li rows, >=128 -> Lj rows
        int r = t & 127;
        const float* src = (t < 128) ? &latent[(size_t)(i0 + r) * 32]
                                     : &latent[(size_t)(j0 + r) * 32];
        float (*dst)[36] = (t < 128) ? Li : Lj;
        #pragma unroll
        for (int q = 0; q < 8; ++q)
            *(float4*)&dst[r][q * 4] = *(const float4*)&src[q * 4];
    }
    __syncthreads();

    const int tx = t & 15, ty = t >> 4;   // rows: ty+16m, cols: tx+16n
    float acc[8][8] = {};
    #pragma unroll
    for (int d4 = 0; d4 < 8; ++d4) {
        float4 bv[8];
        #pragma unroll
        for (int n = 0; n < 8; ++n) bv[n] = *(const float4*)&Lj[tx + 16*n][d4*4];
        #pragma unroll
        for (int m = 0; m < 8; ++m) {
            float4 av = *(const float4*)&Li[ty + 16*m][d4*4];
            #pragma unroll
            for (int n = 0; n < 8; ++n) {
                acc[m][n] = fmaf(av.x, bv[n].x, acc[m][n]);
                acc[m][n] = fmaf(av.y, bv[n].y, acc[m][n]);
                acc[m][n] = fmaf(av.z, bv[n].z, acc[m][n]);
                acc[m][n] = fmaf(av.w, bv[n].w, acc[m][n]);
            }
        }
    }
    float syi[8], syj[8];
    #pragma unroll
    for (int m = 0; m < 8; ++m) syi[m] = sumy[i0 + ty + 16*m];
    #pragma unroll
    for (int n = 0; n < 8; ++n) syj[n] = sumy[j0 + tx + 16*n];

    float racc[8] = {};
    #pragma unroll
    for (int m = 0; m < 8; ++m) {
        const int i = i0 + ty + 16*m;
        #pragma unroll
        for (int n = 0; n < 8; ++n) {
            const int j = j0 + tx + 16*n;
            float sq = syi[m] + syj[n] - 2.0f * acc[m][n];
            float v = 1.0f / (1.0f + sq);
            num_out[(size_t)i * NR + j] = v;
            racc[m] += v;
            if (i == j) diagv[i] = v;
        }
    }
    __syncthreads();
    if (t < 128) scr[t] = 0.f;
    __syncthreads();
    #pragma unroll
    for (int m = 0; m < 8; ++m) atomicAdd(&scr[ty + 16*m], racc[m]);
    __syncthreads();
    if (t < 128) atomicAdd(&rowsum[i0 + t], scr[t]);
}

// ============ fused p+q kernel: one block per row, p kept in registers ============
// p = num/S1 (0 on diag), sp = sum p, sp2 = sum p^2; q = (p^2/sp)/(sp2/sp);
// diagonal of output p and q = diag value.
__global__ __launch_bounds__(256) void pq_kernel(
    const float* __restrict__ num, const float* __restrict__ rowsum,
    const float* __restrict__ diagv, float* __restrict__ p_out,
    float* __restrict__ q_out)
{
    const int i = blockIdx.x;
    const int t = threadIdx.x;
    const float dg = diagv[i];
    const float inv_S1 = 1.0f / (rowsum[i] - dg);
    const float* nrow = &num[(size_t)i * NR];
    float* prow = &p_out[(size_t)i * NR];
    float* qrow = &q_out[(size_t)i * NR];

    float pr[16];
    float s = 0.f, s2 = 0.f;
    #pragma unroll
    for (int it = 0; it < 4; ++it) {
        int j4 = it * 256 + t;
        float4 v = ((const float4*)nrow)[j4];
        float vv[4] = {v.x, v.y, v.z, v.w};
        #pragma unroll
        for (int e = 0; e < 4; ++e) {
            int j = j4 * 4 + e;
            float p = (j == i) ? 0.0f : vv[e] * inv_S1;
            pr[it * 4 + e] = p;
            s += p; s2 += p * p;
        }
        ((float4*)prow)[j4] = make_float4(
            (j4*4+0 == i) ? dg : pr[it*4+0], (j4*4+1 == i) ? dg : pr[it*4+1],
            (j4*4+2 == i) ? dg : pr[it*4+2], (j4*4+3 == i) ? dg : pr[it*4+3]);
    }
    // block reduce (deterministic): full-wave xor reduce, then cross-wave via LDS
    #pragma unroll
    for (int off = 32; off; off >>= 1) {
        s  += __shfl_xor(s, off);
        s2 += __shfl_xor(s2, off);
    }
    __shared__ float rA[4], rB[4];
    const int wid = t >> 6;
    if ((t & 63) == 0) { rA[wid] = s; rB[wid] = s2; }
    __syncthreads();
    const float sp  = rA[0] + rA[1] + rA[2] + rA[3];
    const float sp2 = rB[0] + rB[1] + rB[2] + rB[3];
    const float inv_sp   = 1.0f / sp;
    const float inv_sumq = sp / sp2;     // 1 / (sp2/sp)
    #pragma unroll
    for (int it = 0; it < 4; ++it) {
        int j4 = it * 256 + t;
        float qv[4];
        #pragma unroll
        for (int e = 0; e < 4; ++e) {
            int j = j4 * 4 + e;
            float p = pr[it * 4 + e];
            qv[e] = (j == i) ? dg : (p * p * inv_sp) * inv_sumq;
        }
        ((float4*)qrow)[j4] = make_float4(qv[0], qv[1], qv[2], qv[3]);
    }
}

// ===================== launch =====================
extern "C" void kernel_launch(void* const* d_in, const int* in_sizes, int n_in,
                              void* d_out, int out_size, void* d_ws, size_t ws_size,
                              hipStream_t stream) {
    const float* x       = (const float*)d_in[0];
    const float* W0      = (const float*)d_in[1];
    const float* b0      = (const float*)d_in[2];
    const float* g0      = (const float*)d_in[3];
    const float* beta0   = (const float*)d_in[4];
    const float* W1      = (const float*)d_in[5];
    const float* b1      = (const float*)d_in[6];
    const float* g1      = (const float*)d_in[7];
    const float* beta1   = (const float*)d_in[8];
    const float* W2      = (const float*)d_in[9];
    const float* b2      = (const float*)d_in[10];
    const float* centers = (const float*)d_in[11];
    float* out = (float*)d_out;
    float* ws  = (float*)d_ws;

    // H0/H1 scratch lives in d_out's latent_q region (dead until pq_kernel,
    // which only reads num/rowsum/diag) — d_ws only holds ~85 KB accumulators.
    float* H0 = out + OFF_Q;                 // 4096*256 floats
    float* H1 = out + OFF_Q + 4096 * 256;    // 4096*64 floats

    zero_ws<<<19, 256, 0, stream>>>(ws);     // sum0/sq0/sum1/sq1/rowsum

    h0_init<<<1024, 256, 0, stream>>>(H0, b0);
    gemm_splitk_128x64<<<dim3(32, 4, 5), 256, 0, stream>>>(x, W0, H0, 2000, 2000, 256, 400);
    bn_stats<<<64, 256, 0, stream>>>(H0, ws + WS_SUM0, ws + WS_SQ0, 256);
    bn_relu<<<1024, 256, 0, stream>>>(H0, ws + WS_SUM0, ws + WS_SQ0, g0, beta0, 256);

    gemm_bias_64x64<<<dim3(64, 1), 256, 0, stream>>>(H0, W1, b1, H1, 256, 256, 64, 256);
    bn_stats<<<64, 256, 0, stream>>>(H1, ws + WS_SUM1, ws + WS_SQ1, 64);
    bn_relu<<<256, 256, 0, stream>>>(H1, ws + WS_SUM1, ws + WS_SQ1, g1, beta1, 64);

    latent_kernel<<<512, 256, 0, stream>>>(H1, W2, b2, centers,
        out + OFF_LATENT, out + OFF_NORM, out + OFF_D1, out + OFF_D2, ws + WS_SUMY);

    num_kernel<<<dim3(32, 32), 256, 0, stream>>>(out + OFF_LATENT, ws + WS_SUMY,
        out + OFF_NUM, ws + WS_ROWSUM, ws + WS_DIAG);

    pq_kernel<<<4096, 256, 0, stream>>>(out + OFF_NUM, ws + WS_ROWSUM, ws + WS_DIAG,
        out + OFF_P, out + OFF_Q);
}